// Round 1
// 1274.897 us; speedup vs baseline: 1.0044x; 1.0044x over previous
//
#include <hip/hip_runtime.h>
#include <cstdint>
#include <cstddef>

constexpr int S = 8192;
constexpr int H = 4096;
constexpr int E = 64;
constexpr int CAP = 256;           // ceil(8192*2/64) = 256
constexpr int KSPLIT = 4;
constexpr int KCHUNK = H / KSPLIT; // 1024
constexpr int BK = 32;
constexpr int BM = 64;
constexpr long long SEC = (long long)S * E * CAP; // 134217728

// ---------------------------------------------------------------------------
// K1: fp32 router GEMM  logits[s,e] = sum_k A[s,k] * W[e,k]
// grid (S/BM, KSPLIT), 256 threads. Partials to ws; deterministic reduce in K2.
// fp32 is mandatory: top-2 ordering feeds an order-dependent cumsum — any
// rounding-induced rank flip cascades into wrong slots (absmax 1.0).
// ---------------------------------------------------------------------------
__global__ __launch_bounds__(256)
void k_gemm(const float* __restrict__ A, const float* __restrict__ W,
            float* __restrict__ part) {
    __shared__ float As[BK][BM + 4];
    __shared__ float Bs[BK][E + 4];
    const int tid = threadIdx.x;
    const int m0 = blockIdx.x * BM;
    const int kbase = blockIdx.y * KCHUNK;
    const int lr = tid >> 3;           // 0..31
    const int lc = (tid & 7) << 2;     // 0,4,..,28
    const int ty = tid >> 4;           // 0..15
    const int tx = tid & 15;           // 0..15

    float acc[4][4];
#pragma unroll
    for (int i = 0; i < 4; ++i)
#pragma unroll
        for (int j = 0; j < 4; ++j) acc[i][j] = 0.f;

    for (int kc = 0; kc < KCHUNK; kc += BK) {
        const float* ap = A + (size_t)(m0 + lr) * H + (kbase + kc + lc);
        const float4 av0 = *(const float4*)ap;
        const float4 av1 = *(const float4*)(ap + (size_t)32 * H);
        const float* bp = W + (size_t)lr * H + (kbase + kc + lc);
        const float4 bv0 = *(const float4*)bp;
        const float4 bv1 = *(const float4*)(bp + (size_t)32 * H);
        __syncthreads();
        As[lc + 0][lr] = av0.x; As[lc + 1][lr] = av0.y;
        As[lc + 2][lr] = av0.z; As[lc + 3][lr] = av0.w;
        As[lc + 0][lr + 32] = av1.x; As[lc + 1][lr + 32] = av1.y;
        As[lc + 2][lr + 32] = av1.z; As[lc + 3][lr + 32] = av1.w;
        Bs[lc + 0][lr] = bv0.x; Bs[lc + 1][lr] = bv0.y;
        Bs[lc + 2][lr] = bv0.z; Bs[lc + 3][lr] = bv0.w;
        Bs[lc + 0][lr + 32] = bv1.x; Bs[lc + 1][lr + 32] = bv1.y;
        Bs[lc + 2][lr + 32] = bv1.z; Bs[lc + 3][lr + 32] = bv1.w;
        __syncthreads();
#pragma unroll
        for (int kk = 0; kk < BK; ++kk) {
            const float4 a = *(const float4*)&As[kk][ty * 4];
            const float4 b = *(const float4*)&Bs[kk][tx * 4];
            acc[0][0] = fmaf(a.x, b.x, acc[0][0]);
            acc[0][1] = fmaf(a.x, b.y, acc[0][1]);
            acc[0][2] = fmaf(a.x, b.z, acc[0][2]);
            acc[0][3] = fmaf(a.x, b.w, acc[0][3]);
            acc[1][0] = fmaf(a.y, b.x, acc[1][0]);
            acc[1][1] = fmaf(a.y, b.y, acc[1][1]);
            acc[1][2] = fmaf(a.y, b.z, acc[1][2]);
            acc[1][3] = fmaf(a.y, b.w, acc[1][3]);
            acc[2][0] = fmaf(a.z, b.x, acc[2][0]);
            acc[2][1] = fmaf(a.z, b.y, acc[2][1]);
            acc[2][2] = fmaf(a.z, b.z, acc[2][2]);
            acc[2][3] = fmaf(a.z, b.w, acc[2][3]);
            acc[3][0] = fmaf(a.w, b.x, acc[3][0]);
            acc[3][1] = fmaf(a.w, b.y, acc[3][1]);
            acc[3][2] = fmaf(a.w, b.z, acc[3][2]);
            acc[3][3] = fmaf(a.w, b.w, acc[3][3]);
        }
    }
    float* P = part + (size_t)blockIdx.y * S * E;
#pragma unroll
    for (int i = 0; i < 4; ++i) {
        float4 v = make_float4(acc[i][0], acc[i][1], acc[i][2], acc[i][3]);
        *(float4*)&P[(size_t)(m0 + ty * 4 + i) * E + tx * 4] = v;
    }
}

// ---------------------------------------------------------------------------
// K2: per-token softmax + top-2 (lane = expert). Deterministic KSPLIT reduce.
// ---------------------------------------------------------------------------
__global__ __launch_bounds__(256)
void k_router(const float* __restrict__ part, int* __restrict__ e1a,
              int* __restrict__ e2a, float* __restrict__ g1a,
              float* __restrict__ g2a, float* __restrict__ sumg,
              int* __restrict__ cnt1) {
    const int lane = threadIdx.x & 63;
    const int gw = blockIdx.x * 4 + (threadIdx.x >> 6);
    float lsum = 0.f;
    int lcnt = 0;
    for (int s = gw; s < S; s += 256) {
        const float* p = part + (size_t)s * E + lane;
        float l = p[0] + p[(size_t)S * E] + p[2 * (size_t)S * E]
                + p[3 * (size_t)S * E];
        float m = l;
#pragma unroll
        for (int o = 32; o; o >>= 1) m = fmaxf(m, __shfl_xor(m, o));
        const float ex = __expf(l - m);
        float Z = ex;
#pragma unroll
        for (int o = 32; o; o >>= 1) Z += __shfl_xor(Z, o);
        const float g = ex / Z;
        lsum += g;
        float v1 = g; int i1 = lane;
#pragma unroll
        for (int o = 32; o; o >>= 1) {
            const float ov = __shfl_xor(v1, o);
            const int oi = __shfl_xor(i1, o);
            if (ov > v1 || (ov == v1 && oi < i1)) { v1 = ov; i1 = oi; }
        }
        float v2 = (lane == i1) ? -1.f : g; int i2 = lane;
#pragma unroll
        for (int o = 32; o; o >>= 1) {
            const float ov = __shfl_xor(v2, o);
            const int oi = __shfl_xor(i2, o);
            if (ov > v2 || (ov == v2 && oi < i2)) { v2 = ov; i2 = oi; }
        }
        if (i1 == lane) lcnt++;
        if (lane == 0) {
            e1a[s] = i1; e2a[s] = i2; g1a[s] = v1; g2a[s] = v2;
        }
    }
    atomicAdd(&sumg[lane], lsum);
    atomicAdd(&cnt1[lane], lcnt);
}

// ---------------------------------------------------------------------------
// K3: ordered slot assignment. One wave per expert; ballot+popc = stable rank.
// ---------------------------------------------------------------------------
__global__ __launch_bounds__(64)
void k_assign(const int* __restrict__ e1a, const int* __restrict__ e2a,
              int* __restrict__ slot1a, int* __restrict__ slot2a) {
    const int e = blockIdx.x;
    const int lane = threadIdx.x;
    const unsigned long long below = (1ull << lane) - 1ull;
    int cnt = 0;
    for (int c = 0; c < S; c += 64) {
        const int s = c + lane;
        const bool m = (e1a[s] == e);
        const unsigned long long bal = __ballot(m);
        if (m) {
            const int rank = cnt + __popcll(bal & below);
            slot1a[s] = (rank < CAP) ? rank : -1;
        }
        cnt += __popcll(bal);
    }
    const int total1 = cnt;
    int cnt2 = 0;
    for (int c = 0; c < S; c += 64) {
        const int s = c + lane;
        const bool m = (e2a[s] == e);
        const unsigned long long bal = __ballot(m);
        if (m) {
            const int rank = total1 + cnt2 + __popcll(bal & below);
            slot2a[s] = (rank < CAP) ? rank : -1;
        }
        cnt2 += __popcll(bal);
    }
}

// ---------------------------------------------------------------------------
// K4: scatter <=2 nonzeros per token (post-drop denom, per reference) into
// the pre-zeroed output + l_aux in block 0's first wave.
// ---------------------------------------------------------------------------
__global__ __launch_bounds__(256)
void k_scatter(const int* __restrict__ e1a, const int* __restrict__ e2a,
               const float* __restrict__ g1a, const float* __restrict__ g2a,
               const int* __restrict__ slot1a, const int* __restrict__ slot2a,
               const float* __restrict__ sumg, const int* __restrict__ cnt1,
               float* __restrict__ out) {
    const int s = blockIdx.x * 256 + threadIdx.x;
    float* comb = out + 1;
    float* mask = out + 1 + (size_t)SEC;
    const int sl1 = slot1a[s], sl2 = slot2a[s];
    const float w1 = (sl1 >= 0) ? g1a[s] : 0.f;
    const float w2 = (sl2 >= 0) ? g2a[s] : 0.f;
    const float denom = fmaxf(w1 + w2, 1.1920928955078125e-07f); // FLT_EPSILON
    if (sl1 >= 0) {
        const size_t off = ((size_t)s * E + e1a[s]) * CAP + sl1;
        comb[off] = w1 / denom;
        mask[off] = 1.f;
    }
    if (sl2 >= 0) {
        const size_t off = ((size_t)s * E + e2a[s]) * CAP + sl2;
        comb[off] = w2 / denom;
        mask[off] = 1.f;
    }
    if (blockIdx.x == 0 && threadIdx.x < 64) {
        const int lane = threadIdx.x;
        float v = sumg[lane] * (float)cnt1[lane];
#pragma unroll
        for (int o = 32; o; o >>= 1) v += __shfl_xor(v, o);
        if (lane == 0) out[0] = v * (float)E / ((float)S * (float)S);
    }
}

extern "C" void kernel_launch(void* const* d_in, const int* in_sizes, int n_in,
                              void* d_out, int out_size, void* d_ws,
                              size_t ws_size, hipStream_t stream) {
    const float* A = (const float*)d_in[0];   // gate_input [S,H] fp32
    const float* W = (const float*)d_in[1];   // gate_weight [E,H] fp32
    float* out = (float*)d_out;

    char* ws = (char*)d_ws;
    float* part = (float*)ws;                                   // 8 MB
    size_t off = (size_t)KSPLIT * S * E * sizeof(float);
    int* e1a = (int*)(ws + off);      off += (size_t)S * 4;
    int* e2a = (int*)(ws + off);      off += (size_t)S * 4;
    float* g1a = (float*)(ws + off);  off += (size_t)S * 4;
    float* g2a = (float*)(ws + off);  off += (size_t)S * 4;
    int* slot1a = (int*)(ws + off);   off += (size_t)S * 4;
    int* slot2a = (int*)(ws + off);   off += (size_t)S * 4;
    float* sumg = (float*)(ws + off); off += (size_t)E * 4;
    int* cnt1 = (int*)(ws + off);     off += (size_t)E * 4;

    // rocclr fill (measured 6.2 TB/s) beats every hand-rolled fill we tried
    // (R2 dword-writer +33 µs, R3 barrier-coupled +43, R4 specialized +20).
    hipMemsetAsync(sumg, 0, 2 * (size_t)E * 4, stream);
    // R0 fix: rocprof showed WRITE_SIZE = 4.295 GB per fill = 4x the real
    // output (out_size is in BYTES; the old code multiplied by sizeof(float)).
    // Zero exactly the (1 + 2*SEC) floats the scatter kernel needs zeroed,
    // computed from first principles -- independent of out_size's unit.
    hipMemsetAsync(d_out, 0, sizeof(float) * (size_t)(1 + 2 * SEC), stream);

    k_gemm<<<dim3(S / BM, KSPLIT), 256, 0, stream>>>(A, W, part);
    k_router<<<64, 256, 0, stream>>>(part, e1a, e2a, g1a, g2a, sumg, cnt1);
    k_assign<<<E, 64, 0, stream>>>(e1a, e2a, slot1a, slot2a);
    k_scatter<<<S / 256, 256, 0, stream>>>(e1a, e2a, g1a, g2a, slot1a, slot2a,
                                           sumg, cnt1, out);
}

// Round 2
// 1274.397 us; speedup vs baseline: 1.0048x; 1.0004x over previous
//
#include <hip/hip_runtime.h>
#include <cstdint>
#include <cstddef>

constexpr int S = 8192;
constexpr int H = 4096;
constexpr int E = 64;
constexpr int CAP = 256;           // ceil(8192*2/64) = 256
constexpr int KSPLIT = 8;
constexpr int KCHUNK = H / KSPLIT; // 512
constexpr int BK = 32;
constexpr int BM = 256;
constexpr long long SEC = (long long)S * E * CAP; // 134217728

// ---------------------------------------------------------------------------
// K1: fp32 router GEMM  logits[s,e] = sum_k A[s,k] * W[e,k]
// R1 re-tile: 8x8 per thread (was 4x4). 4 ds_read_b128 feed 64 FMAs
// (16 FMA/b128 vs 8 before) -- the R1 cycle model showed the old tile was
// LDS-issue-bound 3:1 (82 us LDS vs 27 us FMA per CU). BM=256, 256 thr,
// grid (S/BM=32, KSPLIT=8) = 256 blocks = 1/CU.
// fp32 is mandatory: top-2 ordering feeds an order-dependent cumsum — any
// rounding-induced rank flip cascades into wrong slots (absmax 1.0).
// ---------------------------------------------------------------------------
__global__ __launch_bounds__(256)
void k_gemm(const float* __restrict__ A, const float* __restrict__ W,
            float* __restrict__ part) {
    __shared__ float As[BK][BM + 4];   // 32 x 260 floats = 33.3 KB
    __shared__ float Bs[BK][E + 4];    // 32 x 68  floats =  8.7 KB
    const int tid = threadIdx.x;
    const int m0 = blockIdx.x * BM;
    const int kbase = blockIdx.y * KCHUNK;
    const int lr = tid >> 3;           // 0..31
    const int lc = (tid & 7) << 2;     // 0,4,..,28
    const int ty = tid >> 3;           // 0..31 -> 8 rows each (256 rows)
    const int tx = tid & 7;            // 0..7  -> 8 cols each (64 cols)

    float acc[8][8];
#pragma unroll
    for (int i = 0; i < 8; ++i)
#pragma unroll
        for (int j = 0; j < 8; ++j) acc[i][j] = 0.f;

    for (int kc = 0; kc < KCHUNK; kc += BK) {
        // A tile: 256 rows x 32 cols, 8 passes of 32 rows; 8 float4/thread.
        const float* ap = A + (size_t)(m0 + lr) * H + (kbase + kc + lc);
        float4 av[8];
#pragma unroll
        for (int j = 0; j < 8; ++j)
            av[j] = *(const float4*)(ap + (size_t)(32 * j) * H);
        // B tile: 64 rows x 32 cols; 2 float4/thread.
        const float* bp = W + (size_t)lr * H + (kbase + kc + lc);
        const float4 bv0 = *(const float4*)bp;
        const float4 bv1 = *(const float4*)(bp + (size_t)32 * H);
        __syncthreads();
#pragma unroll
        for (int j = 0; j < 8; ++j) {
            As[lc + 0][lr + 32 * j] = av[j].x;
            As[lc + 1][lr + 32 * j] = av[j].y;
            As[lc + 2][lr + 32 * j] = av[j].z;
            As[lc + 3][lr + 32 * j] = av[j].w;
        }
        Bs[lc + 0][lr] = bv0.x; Bs[lc + 1][lr] = bv0.y;
        Bs[lc + 2][lr] = bv0.z; Bs[lc + 3][lr] = bv0.w;
        Bs[lc + 0][lr + 32] = bv1.x; Bs[lc + 1][lr + 32] = bv1.y;
        Bs[lc + 2][lr + 32] = bv1.z; Bs[lc + 3][lr + 32] = bv1.w;
        __syncthreads();
#pragma unroll
        for (int kk = 0; kk < BK; ++kk) {
            const float4 a0 = *(const float4*)&As[kk][ty * 8];
            const float4 a1 = *(const float4*)&As[kk][ty * 8 + 4];
            const float4 b0 = *(const float4*)&Bs[kk][tx * 8];
            const float4 b1 = *(const float4*)&Bs[kk][tx * 8 + 4];
            const float a[8] = {a0.x, a0.y, a0.z, a0.w, a1.x, a1.y, a1.z, a1.w};
            const float b[8] = {b0.x, b0.y, b0.z, b0.w, b1.x, b1.y, b1.z, b1.w};
#pragma unroll
            for (int i = 0; i < 8; ++i)
#pragma unroll
                for (int j = 0; j < 8; ++j)
                    acc[i][j] = fmaf(a[i], b[j], acc[i][j]);
        }
    }
    float* P = part + (size_t)blockIdx.y * S * E;
#pragma unroll
    for (int i = 0; i < 8; ++i) {
        const size_t row = (size_t)(m0 + ty * 8 + i);
        float4 v0 = make_float4(acc[i][0], acc[i][1], acc[i][2], acc[i][3]);
        float4 v1 = make_float4(acc[i][4], acc[i][5], acc[i][6], acc[i][7]);
        *(float4*)&P[row * E + tx * 8] = v0;
        *(float4*)&P[row * E + tx * 8 + 4] = v1;
    }
}

// ---------------------------------------------------------------------------
// K2: per-token softmax + top-2 (lane = expert). Deterministic KSPLIT reduce.
// ---------------------------------------------------------------------------
__global__ __launch_bounds__(256)
void k_router(const float* __restrict__ part, int* __restrict__ e1a,
              int* __restrict__ e2a, float* __restrict__ g1a,
              float* __restrict__ g2a, float* __restrict__ sumg,
              int* __restrict__ cnt1) {
    const int lane = threadIdx.x & 63;
    const int gw = blockIdx.x * 4 + (threadIdx.x >> 6);
    float lsum = 0.f;
    int lcnt = 0;
    for (int s = gw; s < S; s += 256) {
        const float* p = part + (size_t)s * E + lane;
        float l = 0.f;
#pragma unroll
        for (int j = 0; j < KSPLIT; ++j)   // fixed order: deterministic
            l += p[(size_t)j * S * E];
        float m = l;
#pragma unroll
        for (int o = 32; o; o >>= 1) m = fmaxf(m, __shfl_xor(m, o));
        const float ex = __expf(l - m);
        float Z = ex;
#pragma unroll
        for (int o = 32; o; o >>= 1) Z += __shfl_xor(Z, o);
        const float g = ex / Z;
        lsum += g;
        float v1 = g; int i1 = lane;
#pragma unroll
        for (int o = 32; o; o >>= 1) {
            const float ov = __shfl_xor(v1, o);
            const int oi = __shfl_xor(i1, o);
            if (ov > v1 || (ov == v1 && oi < i1)) { v1 = ov; i1 = oi; }
        }
        float v2 = (lane == i1) ? -1.f : g; int i2 = lane;
#pragma unroll
        for (int o = 32; o; o >>= 1) {
            const float ov = __shfl_xor(v2, o);
            const int oi = __shfl_xor(i2, o);
            if (ov > v2 || (ov == v2 && oi < i2)) { v2 = ov; i2 = oi; }
        }
        if (i1 == lane) lcnt++;
        if (lane == 0) {
            e1a[s] = i1; e2a[s] = i2; g1a[s] = v1; g2a[s] = v2;
        }
    }
    atomicAdd(&sumg[lane], lsum);
    atomicAdd(&cnt1[lane], lcnt);
}

// ---------------------------------------------------------------------------
// K3: ordered slot assignment. One wave per expert; ballot+popc = stable rank.
// ---------------------------------------------------------------------------
__global__ __launch_bounds__(64)
void k_assign(const int* __restrict__ e1a, const int* __restrict__ e2a,
              int* __restrict__ slot1a, int* __restrict__ slot2a) {
    const int e = blockIdx.x;
    const int lane = threadIdx.x;
    const unsigned long long below = (1ull << lane) - 1ull;
    int cnt = 0;
    for (int c = 0; c < S; c += 64) {
        const int s = c + lane;
        const bool m = (e1a[s] == e);
        const unsigned long long bal = __ballot(m);
        if (m) {
            const int rank = cnt + __popcll(bal & below);
            slot1a[s] = (rank < CAP) ? rank : -1;
        }
        cnt += __popcll(bal);
    }
    const int total1 = cnt;
    int cnt2 = 0;
    for (int c = 0; c < S; c += 64) {
        const int s = c + lane;
        const bool m = (e2a[s] == e);
        const unsigned long long bal = __ballot(m);
        if (m) {
            const int rank = total1 + cnt2 + __popcll(bal & below);
            slot2a[s] = (rank < CAP) ? rank : -1;
        }
        cnt2 += __popcll(bal);
    }
}

// ---------------------------------------------------------------------------
// K4: scatter <=2 nonzeros per token (post-drop denom, per reference) into
// the pre-zeroed output + l_aux in block 0's first wave.
// ---------------------------------------------------------------------------
__global__ __launch_bounds__(256)
void k_scatter(const int* __restrict__ e1a, const int* __restrict__ e2a,
               const float* __restrict__ g1a, const float* __restrict__ g2a,
               const int* __restrict__ slot1a, const int* __restrict__ slot2a,
               const float* __restrict__ sumg, const int* __restrict__ cnt1,
               float* __restrict__ out) {
    const int s = blockIdx.x * 256 + threadIdx.x;
    float* comb = out + 1;
    float* mask = out + 1 + (size_t)SEC;
    const int sl1 = slot1a[s], sl2 = slot2a[s];
    const float w1 = (sl1 >= 0) ? g1a[s] : 0.f;
    const float w2 = (sl2 >= 0) ? g2a[s] : 0.f;
    const float denom = fmaxf(w1 + w2, 1.1920928955078125e-07f); // FLT_EPSILON
    if (sl1 >= 0) {
        const size_t off = ((size_t)s * E + e1a[s]) * CAP + sl1;
        comb[off] = w1 / denom;
        mask[off] = 1.f;
    }
    if (sl2 >= 0) {
        const size_t off = ((size_t)s * E + e2a[s]) * CAP + sl2;
        comb[off] = w2 / denom;
        mask[off] = 1.f;
    }
    if (blockIdx.x == 0 && threadIdx.x < 64) {
        const int lane = threadIdx.x;
        float v = sumg[lane] * (float)cnt1[lane];
#pragma unroll
        for (int o = 32; o; o >>= 1) v += __shfl_xor(v, o);
        if (lane == 0) out[0] = v * (float)E / ((float)S * (float)S);
    }
}

extern "C" void kernel_launch(void* const* d_in, const int* in_sizes, int n_in,
                              void* d_out, int out_size, void* d_ws,
                              size_t ws_size, hipStream_t stream) {
    const float* A = (const float*)d_in[0];   // gate_input [S,H] fp32
    const float* W = (const float*)d_in[1];   // gate_weight [E,H] fp32
    float* out = (float*)d_out;

    char* ws = (char*)d_ws;
    float* part = (float*)ws;                                   // 16 MB
    size_t off = (size_t)KSPLIT * S * E * sizeof(float);
    int* e1a = (int*)(ws + off);      off += (size_t)S * 4;
    int* e2a = (int*)(ws + off);      off += (size_t)S * 4;
    float* g1a = (float*)(ws + off);  off += (size_t)S * 4;
    float* g2a = (float*)(ws + off);  off += (size_t)S * 4;
    int* slot1a = (int*)(ws + off);   off += (size_t)S * 4;
    int* slot2a = (int*)(ws + off);   off += (size_t)S * 4;
    float* sumg = (float*)(ws + off); off += (size_t)E * 4;
    int* cnt1 = (int*)(ws + off);     off += (size_t)E * 4;

    // rocclr fill (measured 6.2 TB/s) beats every hand-rolled fill we tried
    // (R2 dword-writer +33 µs, R3 barrier-coupled +43, R4 specialized +20).
    hipMemsetAsync(sumg, 0, 2 * (size_t)E * 4, stream);
    // R1 note: out_size is in ELEMENTS (R0's explicit-byte fix was a no-op;
    // WRITE_SIZE/dur unchanged). The 4.295 GB ~690 us fill in the profile is
    // the harness's per-iteration re-poison (2^32 bytes), not ours. Our fill
    // below is 1.07 GB -- mandatory output traffic, already at BW floor.
    hipMemsetAsync(d_out, 0, sizeof(float) * (size_t)(1 + 2 * SEC), stream);

    k_gemm<<<dim3(S / BM, KSPLIT), 256, 0, stream>>>(A, W, part);
    k_router<<<64, 256, 0, stream>>>(part, e1a, e2a, g1a, g2a, sumg, cnt1);
    k_assign<<<E, 64, 0, stream>>>(e1a, e2a, slot1a, slot2a);
    k_scatter<<<S / 256, 256, 0, stream>>>(e1a, e2a, g1a, g2a, slot1a, slot2a,
                                           sumg, cnt1, out);
}

// Round 4
// 1223.960 us; speedup vs baseline: 1.0462x; 1.0412x over previous
//
#include <hip/hip_runtime.h>
#include <cstdint>
#include <cstddef>

constexpr int S = 8192;
constexpr int H = 4096;
constexpr int E = 64;
constexpr int CAP = 256;           // ceil(8192*2/64) = 256
constexpr int KSPLIT = 8;
constexpr int KCHUNK = H / KSPLIT; // 512
constexpr int BK = 32;
constexpr int BM = 256;
constexpr long long SEC = (long long)S * E * CAP; // 134217728

// ---------------------------------------------------------------------------
// K1: fp32 router GEMM  logits[s,e] = sum_k A[s,k] * W[e,k]
// 8x8/thread, BM=256, grid (32, KSPLIT=8). ~40 us, FMA-bound (per-wave:
// 4 ds_read_b128 = 48 cyc vs 64 FMA = 128 cyc per kk-pair). R0-R2 showed
// totals are insensitive to GEMM structure (4x4 vs 8x8 identical) -- leave it.
// fp32 is mandatory: top-2 ordering feeds an order-dependent cumsum — any
// rounding-induced rank flip cascades into wrong slots (absmax 1.0).
// Block (0,0) also zeroes the sumg/cnt1 accumulators (saves a dispatch;
// kernel-boundary ordering guarantees visibility before k_router's atomics).
// ---------------------------------------------------------------------------
__global__ __launch_bounds__(256)
void k_gemm(const float* __restrict__ A, const float* __restrict__ W,
            float* __restrict__ part, float* __restrict__ sumg,
            int* __restrict__ cnt1) {
    __shared__ float As[BK][BM + 4];   // 32 x 260 floats = 33.3 KB
    __shared__ float Bs[BK][E + 4];    // 32 x 68  floats =  8.7 KB
    const int tid = threadIdx.x;
    if (blockIdx.x == 0 && blockIdx.y == 0) {
        if (tid < 64) sumg[tid] = 0.f;
        else if (tid < 128) cnt1[tid - 64] = 0;
    }
    const int m0 = blockIdx.x * BM;
    const int kbase = blockIdx.y * KCHUNK;
    const int lr = tid >> 3;           // 0..31
    const int lc = (tid & 7) << 2;     // 0,4,..,28
    const int ty = tid >> 3;           // 0..31 -> 8 rows each (256 rows)
    const int tx = tid & 7;            // 0..7  -> 8 cols each (64 cols)

    float acc[8][8];
#pragma unroll
    for (int i = 0; i < 8; ++i)
#pragma unroll
        for (int j = 0; j < 8; ++j) acc[i][j] = 0.f;

    for (int kc = 0; kc < KCHUNK; kc += BK) {
        // A tile: 256 rows x 32 cols, 8 passes of 32 rows; 8 float4/thread.
        const float* ap = A + (size_t)(m0 + lr) * H + (kbase + kc + lc);
        float4 av[8];
#pragma unroll
        for (int j = 0; j < 8; ++j)
            av[j] = *(const float4*)(ap + (size_t)(32 * j) * H);
        // B tile: 64 rows x 32 cols; 2 float4/thread.
        const float* bp = W + (size_t)lr * H + (kbase + kc + lc);
        const float4 bv0 = *(const float4*)bp;
        const float4 bv1 = *(const float4*)(bp + (size_t)32 * H);
        __syncthreads();
#pragma unroll
        for (int j = 0; j < 8; ++j) {
            As[lc + 0][lr + 32 * j] = av[j].x;
            As[lc + 1][lr + 32 * j] = av[j].y;
            As[lc + 2][lr + 32 * j] = av[j].z;
            As[lc + 3][lr + 32 * j] = av[j].w;
        }
        Bs[lc + 0][lr] = bv0.x; Bs[lc + 1][lr] = bv0.y;
        Bs[lc + 2][lr] = bv0.z; Bs[lc + 3][lr] = bv0.w;
        Bs[lc + 0][lr + 32] = bv1.x; Bs[lc + 1][lr + 32] = bv1.y;
        Bs[lc + 2][lr + 32] = bv1.z; Bs[lc + 3][lr + 32] = bv1.w;
        __syncthreads();
#pragma unroll
        for (int kk = 0; kk < BK; ++kk) {
            const float4 a0 = *(const float4*)&As[kk][ty * 8];
            const float4 a1 = *(const float4*)&As[kk][ty * 8 + 4];
            const float4 b0 = *(const float4*)&Bs[kk][tx * 8];
            const float4 b1 = *(const float4*)&Bs[kk][tx * 8 + 4];
            const float a[8] = {a0.x, a0.y, a0.z, a0.w, a1.x, a1.y, a1.z, a1.w};
            const float b[8] = {b0.x, b0.y, b0.z, b0.w, b1.x, b1.y, b1.z, b1.w};
#pragma unroll
            for (int i = 0; i < 8; ++i)
#pragma unroll
                for (int j = 0; j < 8; ++j)
                    acc[i][j] = fmaf(a[i], b[j], acc[i][j]);
        }
    }
    float* P = part + (size_t)blockIdx.y * S * E;
#pragma unroll
    for (int i = 0; i < 8; ++i) {
        const size_t row = (size_t)(m0 + ty * 8 + i);
        float4 v0 = make_float4(acc[i][0], acc[i][1], acc[i][2], acc[i][3]);
        float4 v1 = make_float4(acc[i][4], acc[i][5], acc[i][6], acc[i][7]);
        *(float4*)&P[row * E + tx * 8] = v0;
        *(float4*)&P[row * E + tx * 8 + 4] = v1;
    }
}

// ---------------------------------------------------------------------------
// K2: per-token softmax + top-2 (lane = expert). Deterministic KSPLIT reduce.
// ---------------------------------------------------------------------------
__global__ __launch_bounds__(256)
void k_router(const float* __restrict__ part, int* __restrict__ e1a,
              int* __restrict__ e2a, float* __restrict__ g1a,
              float* __restrict__ g2a, float* __restrict__ sumg,
              int* __restrict__ cnt1) {
    const int lane = threadIdx.x & 63;
    const int gw = blockIdx.x * 4 + (threadIdx.x >> 6);
    float lsum = 0.f;
    int lcnt = 0;
    for (int s = gw; s < S; s += 256) {
        const float* p = part + (size_t)s * E + lane;
        float l = 0.f;
#pragma unroll
        for (int j = 0; j < KSPLIT; ++j)   // fixed order: deterministic
            l += p[(size_t)j * S * E];
        float m = l;
#pragma unroll
        for (int o = 32; o; o >>= 1) m = fmaxf(m, __shfl_xor(m, o));
        const float ex = __expf(l - m);
        float Z = ex;
#pragma unroll
        for (int o = 32; o; o >>= 1) Z += __shfl_xor(Z, o);
        const float g = ex / Z;
        lsum += g;
        float v1 = g; int i1 = lane;
#pragma unroll
        for (int o = 32; o; o >>= 1) {
            const float ov = __shfl_xor(v1, o);
            const int oi = __shfl_xor(i1, o);
            if (ov > v1 || (ov == v1 && oi < i1)) { v1 = ov; i1 = oi; }
        }
        float v2 = (lane == i1) ? -1.f : g; int i2 = lane;
#pragma unroll
        for (int o = 32; o; o >>= 1) {
            const float ov = __shfl_xor(v2, o);
            const int oi = __shfl_xor(i2, o);
            if (ov > v2 || (ov == v2 && oi < i2)) { v2 = ov; i2 = oi; }
        }
        if (i1 == lane) lcnt++;
        if (lane == 0) {
            e1a[s] = i1; e2a[s] = i2; g1a[s] = v1; g2a[s] = v2;
        }
    }
    atomicAdd(&sumg[lane], lsum);
    atomicAdd(&cnt1[lane], lcnt);
}

// ---------------------------------------------------------------------------
// K3 v2 (R2): ordered slot assignment, latency-attacked.
// Old shape: 1 wave/block, 128 serial load->ballot steps x 2 passes.
// New: 4 waves/block, ONE fused scan (mask1+mask2 prefixes computed together;
// the reference's "loc2 += sum(mask1)" total-count offset is deferred to K4
// via tot1[e]), cross-wave prefix through LDS, next-chunk prefetch.
// 256 serial steps -> 32 pipelined steps. Rank order (s-ordered, stable
// intra-ballot) is IDENTICAL to the reference cumsum.
// ---------------------------------------------------------------------------
__global__ __launch_bounds__(256)
void k_assign(const int* __restrict__ e1a, const int* __restrict__ e2a,
              int* __restrict__ slot1a, int* __restrict__ slot2a,
              int* __restrict__ tot1) {
    const int e = blockIdx.x;
    const int tid = threadIdx.x;
    const int lane = tid & 63;
    const int w = tid >> 6;                 // wave 0..3
    __shared__ int c1[4], c2[4];
    const unsigned long long below = (1ull << lane) - 1ull;
    int cnt1 = 0, cnt2 = 0;                 // block-wide running totals
    int v1 = e1a[tid], v2 = e2a[tid];       // prefetched chunk 0
    for (int c = 0; c < S; c += 256) {
        const int s = c + tid;
        const int cur1 = v1, cur2 = v2;
        if (c + 256 < S) {                  // prefetch next chunk early
            v1 = e1a[s + 256];
            v2 = e2a[s + 256];
        }
        const bool m1 = (cur1 == e);
        const bool m2 = (cur2 == e);
        const unsigned long long b1 = __ballot(m1);
        const unsigned long long b2 = __ballot(m2);
        if (lane == 0) { c1[w] = __popcll(b1); c2[w] = __popcll(b2); }
        __syncthreads();
        int pre1 = 0, pre2 = 0, t1 = 0, t2 = 0;
#pragma unroll
        for (int i = 0; i < 4; ++i) {
            const int x1 = c1[i], x2 = c2[i];
            if (i < w) { pre1 += x1; pre2 += x2; }
            t1 += x1; t2 += x2;
        }
        if (m1) {
            const int r = cnt1 + pre1 + __popcll(b1 & below);
            slot1a[s] = (r < CAP) ? r : -1;
        }
        if (m2) {
            // raw rank within mask2; final rank = tot1[e] + raw (checked in K4)
            slot2a[s] = cnt2 + pre2 + __popcll(b2 & below);
        }
        cnt1 += t1; cnt2 += t2;
        __syncthreads();                    // c1/c2 reused next iteration
    }
    if (tid == 0) tot1[e] = cnt1;           // full (uncapped) mask1 count
}

// ---------------------------------------------------------------------------
// K4: scatter <=2 nonzeros per token (post-drop denom, per reference) into
// the pre-zeroed output + l_aux in block 0's first wave.
// slot2 capacity check done here: rank2 = tot1[e2] + raw2 (reference's
// loc2 = cumsum(mask2)-1 + sum(mask1)).
// ---------------------------------------------------------------------------
__global__ __launch_bounds__(256)
void k_scatter(const int* __restrict__ e1a, const int* __restrict__ e2a,
               const float* __restrict__ g1a, const float* __restrict__ g2a,
               const int* __restrict__ slot1a, const int* __restrict__ slot2a,
               const int* __restrict__ tot1, const float* __restrict__ sumg,
               const int* __restrict__ cnt1, float* __restrict__ out) {
    const int s = blockIdx.x * 256 + threadIdx.x;
    float* comb = out + 1;
    float* mask = out + 1 + (size_t)SEC;
    const int e2 = e2a[s];
    const int sl1 = slot1a[s];
    const int r2 = slot2a[s] + tot1[e2];    // final mask2 rank
    const bool ok2 = (r2 < CAP);
    const float w1 = (sl1 >= 0) ? g1a[s] : 0.f;
    const float w2 = ok2 ? g2a[s] : 0.f;
    const float denom = fmaxf(w1 + w2, 1.1920928955078125e-07f); // FLT_EPSILON
    if (sl1 >= 0) {
        const size_t off = ((size_t)s * E + e1a[s]) * CAP + sl1;
        comb[off] = w1 / denom;
        mask[off] = 1.f;
    }
    if (ok2) {
        const size_t off = ((size_t)s * E + e2) * CAP + r2;
        comb[off] = w2 / denom;
        mask[off] = 1.f;
    }
    if (blockIdx.x == 0 && threadIdx.x < 64) {
        const int lane = threadIdx.x;
        float v = sumg[lane] * (float)cnt1[lane];
#pragma unroll
        for (int o = 32; o; o >>= 1) v += __shfl_xor(v, o);
        if (lane == 0) out[0] = v * (float)E / ((float)S * (float)S);
    }
}

extern "C" void kernel_launch(void* const* d_in, const int* in_sizes, int n_in,
                              void* d_out, int out_size, void* d_ws,
                              size_t ws_size, hipStream_t stream) {
    const float* A = (const float*)d_in[0];   // gate_input [S,H] fp32
    const float* W = (const float*)d_in[1];   // gate_weight [E,H] fp32
    float* out = (float*)d_out;

    char* ws = (char*)d_ws;
    float* part = (float*)ws;                                   // 16.8 MB
    size_t off = (size_t)KSPLIT * S * E * sizeof(float);
    int* e1a = (int*)(ws + off);      off += (size_t)S * 4;
    int* e2a = (int*)(ws + off);      off += (size_t)S * 4;
    float* g1a = (float*)(ws + off);  off += (size_t)S * 4;
    float* g2a = (float*)(ws + off);  off += (size_t)S * 4;
    int* slot1a = (int*)(ws + off);   off += (size_t)S * 4;
    int* slot2a = (int*)(ws + off);   off += (size_t)S * 4;
    float* sumg = (float*)(ws + off); off += (size_t)E * 4;
    int* cnt1 = (int*)(ws + off);     off += (size_t)E * 4;
    int* tot1 = (int*)(ws + off);     off += (size_t)E * 4;

    // R1/R2 notes: the 4.295 GB (2^32 B) ~690 us fill in every profile is the
    // harness's per-iteration workspace re-poison -- fixed cost, not ours.
    // Our only big fill is the mandatory 1.07 GB output zero below (rocclr
    // fill measured 6.2 TB/s = BW floor; hand-rolled fills all lost).
    // sumg/cnt1 zeroing is folded into k_gemm block (0,0) -- one less dispatch.
    // R3: resubmit of R2 unchanged -- container failed twice (infra flake,
    // no compile/absmax/timeout signature; k_assign barriers are uniform).
    hipMemsetAsync(d_out, 0, sizeof(float) * (size_t)(1 + 2 * SEC), stream);

    k_gemm<<<dim3(S / BM, KSPLIT), 256, 0, stream>>>(A, W, part, sumg, cnt1);
    k_router<<<64, 256, 0, stream>>>(part, e1a, e2a, g1a, g2a, sumg, cnt1);
    k_assign<<<E, 256, 0, stream>>>(e1a, e2a, slot1a, slot2a, tot1);
    k_scatter<<<S / 256, 256, 0, stream>>>(e1a, e2a, g1a, g2a, slot1a, slot2a,
                                           tot1, sumg, cnt1, out);
}